// Round 2
// baseline (227.081 us; speedup 1.0000x reference)
//
#include <hip/hip_runtime.h>

// Problem constants
constexpr int BATCH = 64;     // M
constexpr int IC    = 8192;   // K
constexpr int OC    = 8192;   // N
constexpr int OCH   = 4096;   // packed rows (OC/2)
constexpr int KSPLIT = 8;
constexpr int KPER  = IC / KSPLIT;   // 1024
constexpr int BK    = 64;            // K-chunk staged in LDS
constexpr int NITER = KPER / BK;     // 16
constexpr int LDK   = BK + 8;        // 72: row stride 144B -> uniform bank spread (verified arithmetic)

typedef __bf16 bf16x8 __attribute__((ext_vector_type(8)));
typedef float  f32x4  __attribute__((ext_vector_type(4)));

// fp32 -> bf16 round-to-nearest-even
static __device__ __forceinline__ unsigned short f2bf(float f) {
    unsigned u = __float_as_uint(f);
    u += 0x7FFFu + ((u >> 16) & 1u);
    return (unsigned short)(u >> 16);
}

// (bf16(n1)<<16) | bf16(n0) for small ints 0..15: fp32 truncation is exact,
// v_perm_b32 grabs the two high halves in one op.
static __device__ __forceinline__ unsigned pack2bf(int n0, int n1) {
    unsigned f0 = __float_as_uint((float)n0);
    unsigned f1 = __float_as_uint((float)n1);
    return __builtin_amdgcn_perm(f1, f0, 0x07060302u);
}

// ---------------------------------------------------------------------------
// Prep: input fp32 [64,8192] -> bf16 in ws, plus per-row sums S[64]
// ---------------------------------------------------------------------------
__global__ __launch_bounds__(256) void prep_kernel(
    const float* __restrict__ in, unsigned short* __restrict__ Abf,
    float* __restrict__ S)
{
    const int b = blockIdx.x;
    const int t = threadIdx.x;
    const float* row = in + (size_t)b * IC;
    unsigned short* orow = Abf + (size_t)b * IC;

    float sum = 0.f;
#pragma unroll
    for (int i = 0; i < IC / 1024; ++i) {
        const int c = i * 1024 + t * 4;
        const float4 v = *(const float4*)(row + c);
        sum += (v.x + v.y) + (v.z + v.w);
        ushort4 o = make_ushort4(f2bf(v.x), f2bf(v.y), f2bf(v.z), f2bf(v.w));
        *(ushort4*)(orow + c) = o;
    }
#pragma unroll
    for (int off = 32; off > 0; off >>= 1) sum += __shfl_down(sum, off);

    __shared__ float red[4];
    if ((t & 63) == 0) red[t >> 6] = sum;
    __syncthreads();
    if (t == 0) S[b] = (red[0] + red[1]) + (red[2] + red[3]);
}

// ---------------------------------------------------------------------------
// GEMM: out[64,8192] += delta*(A.Q^T) with affine const folded per split.
// 1024 blocks (128 n-tiles x 8 k-splits) = 4 blocks/CU, fully co-resident.
// Tile: M=64 x N=64 (lo+hi nibbles of 32 packed rows, each int32 read once).
// K-loop is register-double-buffered: loads for iter k+1 issue before the
// MFMA phase of iter k, hiding global latency behind compute + barriers.
// ---------------------------------------------------------------------------
__global__ __launch_bounds__(256, 4) void gemm_kernel(
    const unsigned short* __restrict__ Abf,   // bf16 [64][8192]
    const int* __restrict__ wp,               // packed [4096][8192]
    const float* __restrict__ delta,
    const float* __restrict__ zp,
    const float* __restrict__ bias,
    const float* __restrict__ S,              // [64]
    float* __restrict__ out)                  // fp32 [64][8192], pre-zeroed
{
    __shared__ unsigned short lA[64 * LDK];
    __shared__ unsigned short lW[64 * LDK];   // rows 0..31 lo nibble, 32..63 hi

    const int t    = threadIdx.x;
    const int wave = t >> 6;
    const int lane = t & 63;
    const int lm   = lane & 15;
    const int lq   = lane >> 4;

    const int nt  = blockIdx.x & 127;
    const int ks  = blockIdx.x >> 7;
    const int r0  = nt * 32;
    const int kb0 = ks * KPER;

    f32x4 acc[4];
    const f32x4 zero4 = {0.f, 0.f, 0.f, 0.f};
#pragma unroll
    for (int i = 0; i < 4; ++i) acc[i] = zero4;

    // staging maps: A: 64 rows x 4 segs of 16 bf16; W: 32 rows x 8 segs of 8 ints
    const int uAr = t >> 2, uAc = (t & 3) * 16;
    const int uWr = t >> 3, uWc = (t & 7) * 8;

    const unsigned short* pA = Abf + (size_t)uAr * IC + kb0 + uAc;
    const int*            pW = wp  + (size_t)(r0 + uWr) * IC + kb0 + uWc;

    // preload iter 0
    int4 a0 = *(const int4*)(pA);
    int4 a1 = *(const int4*)(pA + 8);
    int4 w0 = *(const int4*)(pW);
    int4 w1 = *(const int4*)(pW + 4);

    for (int it = 0; it < NITER; ++it) {
        __syncthreads();   // previous iteration's LDS reads complete

        *(int4*)(&lA[uAr * LDK + uAc])     = a0;
        *(int4*)(&lA[uAr * LDK + uAc + 8]) = a1;

        int4 lo, hi;
        lo.x = pack2bf( w0.x       & 15,  w0.y       & 15);
        lo.y = pack2bf( w0.z       & 15,  w0.w       & 15);
        lo.z = pack2bf( w1.x       & 15,  w1.y       & 15);
        lo.w = pack2bf( w1.z       & 15,  w1.w       & 15);
        hi.x = pack2bf((w0.x >> 4) & 15, (w0.y >> 4) & 15);
        hi.y = pack2bf((w0.z >> 4) & 15, (w0.w >> 4) & 15);
        hi.z = pack2bf((w1.x >> 4) & 15, (w1.y >> 4) & 15);
        hi.w = pack2bf((w1.z >> 4) & 15, (w1.w >> 4) & 15);
        *(int4*)(&lW[uWr        * LDK + uWc]) = lo;
        *(int4*)(&lW[(uWr + 32) * LDK + uWc]) = hi;

        __syncthreads();

        // preload next iter (clamped/wrapped on last iter; values unused)
        {
            const int koff = ((it + 1) & (NITER - 1)) * BK;
            a0 = *(const int4*)(pA + koff);
            a1 = *(const int4*)(pA + koff + 8);
            w0 = *(const int4*)(pW + koff);
            w1 = *(const int4*)(pW + koff + 4);
        }

#pragma unroll
        for (int s = 0; s < 2; ++s) {
            const int kc = s * 32 + lq * 8;
            const bf16x8 bfrg = *(const bf16x8*)(&lW[(wave * 16 + lm) * LDK + kc]);
#pragma unroll
            for (int mt = 0; mt < 4; ++mt) {
                const bf16x8 afrg = *(const bf16x8*)(&lA[(mt * 16 + lm) * LDK + kc]);
                acc[mt] = __builtin_amdgcn_mfma_f32_16x16x32_bf16(afrg, bfrg, acc[mt], 0, 0, 0);
            }
        }
    }

    // Epilogue: C/D layout col(n) = lane&15, row(m within tile) = lq*4 + reg
    const int cr = wave * 16 + lm;
    const int ch = (cr < 32) ? (r0 + cr) : (OCH + r0 + (cr - 32));
    const float d  = delta[ch];
    const float dz = d * zp[ch];
    const float bi = bias[ch];
    constexpr float inv_split = 1.f / (float)KSPLIT;

#pragma unroll
    for (int mt = 0; mt < 4; ++mt) {
#pragma unroll
        for (int r = 0; r < 4; ++r) {
            const int m = mt * 16 + lq * 4 + r;
            const float res = d * acc[mt][r] + (bi - dz * S[m]) * inv_split;
            atomicAdd(out + (size_t)m * OC + ch, res);
        }
    }
}

extern "C" void kernel_launch(void* const* d_in, const int* in_sizes, int n_in,
                              void* d_out, int out_size, void* d_ws, size_t ws_size,
                              hipStream_t stream) {
    const float* input = (const float*)d_in[0];
    const int*   wpk   = (const int*)d_in[1];
    const float* delta = (const float*)d_in[2];
    const float* zp    = (const float*)d_in[3];
    const float* bias  = (const float*)d_in[4];
    float* out = (float*)d_out;

    unsigned short* Abf = (unsigned short*)d_ws;                      // 1 MiB bf16 A
    float* S = (float*)((char*)d_ws + (size_t)BATCH * IC * 2);        // 64 floats

    hipMemsetAsync(d_out, 0, (size_t)out_size * sizeof(float), stream);
    prep_kernel<<<dim3(BATCH), dim3(256), 0, stream>>>(input, Abf, S);
    gemm_kernel<<<dim3(128 * KSPLIT), dim3(256), 0, stream>>>(Abf, wpk, delta, zp, bias, S, out);
}

// Round 3
// 225.353 us; speedup vs baseline: 1.0077x; 1.0077x over previous
//
#include <hip/hip_runtime.h>

// Problem constants
constexpr int BATCH = 64;     // M
constexpr int IC    = 8192;   // K
constexpr int OC    = 8192;   // N
constexpr int OCH   = 4096;   // packed rows (OC/2)
constexpr int KSPLIT = 8;
constexpr int KPER  = IC / KSPLIT;   // 1024
constexpr int BK    = 64;            // K-chunk staged in LDS
constexpr int NITER = KPER / BK;     // 16
constexpr int LDK   = BK + 8;        // 72: 144B row stride, uniform bank spread

typedef __bf16 bf16x8 __attribute__((ext_vector_type(8)));
typedef float  f32x4  __attribute__((ext_vector_type(4)));

// fp32 -> bf16 round-to-nearest-even
static __device__ __forceinline__ unsigned short f2bf(float f) {
    unsigned u = __float_as_uint(f);
    u += 0x7FFFu + ((u >> 16) & 1u);
    return (unsigned short)(u >> 16);
}

// (bf16(n1)<<16) | bf16(n0) for small ints 0..15 (fp32 truncation exact)
static __device__ __forceinline__ unsigned pack2bf(int n0, int n1) {
    unsigned f0 = __float_as_uint((float)n0);
    unsigned f1 = __float_as_uint((float)n1);
    return __builtin_amdgcn_perm(f1, f0, 0x07060302u);
}

// ---------------------------------------------------------------------------
// Prep: input fp32 [64,8192] -> bf16 in ws, plus per-row sums S[64]
// ---------------------------------------------------------------------------
__global__ __launch_bounds__(256) void prep_kernel(
    const float* __restrict__ in, unsigned short* __restrict__ Abf,
    float* __restrict__ S)
{
    const int b = blockIdx.x;
    const int t = threadIdx.x;
    const float* row = in + (size_t)b * IC;
    unsigned short* orow = Abf + (size_t)b * IC;

    float sum = 0.f;
#pragma unroll
    for (int i = 0; i < IC / 1024; ++i) {
        const int c = i * 1024 + t * 4;
        const float4 v = *(const float4*)(row + c);
        sum += (v.x + v.y) + (v.z + v.w);
        ushort4 o = make_ushort4(f2bf(v.x), f2bf(v.y), f2bf(v.z), f2bf(v.w));
        *(ushort4*)(orow + c) = o;
    }
#pragma unroll
    for (int off = 32; off > 0; off >>= 1) sum += __shfl_down(sum, off);

    __shared__ float red[4];
    if ((t & 63) == 0) red[t >> 6] = sum;
    __syncthreads();
    if (t == 0) S[b] = (red[0] + red[1]) + (red[2] + red[3]);
}

// ---------------------------------------------------------------------------
// GEMM: partial[ks][64][8192] = A.Q^T over this split's K-range. No atomics,
// no affine math here — raw integer-dot sums (in bf16 MFMA, fp32 acc).
// 1024 blocks (128 n-tiles x 8 k-splits). Tile M=64 x N=64 (lo+hi nibbles of
// 32 packed rows; each packed int32 fetched exactly once device-wide).
// Register-double-buffered K-loop.
// ---------------------------------------------------------------------------
__global__ __launch_bounds__(256, 4) void gemm_kernel(
    const unsigned short* __restrict__ Abf,   // bf16 [64][8192]
    const int* __restrict__ wp,               // packed [4096][8192]
    float* __restrict__ part)                 // fp32 [KSPLIT][64][8192]
{
    __shared__ unsigned short lA[64 * LDK];
    __shared__ unsigned short lW[64 * LDK];   // rows 0..31 lo nibble, 32..63 hi

    const int t    = threadIdx.x;
    const int wave = t >> 6;
    const int lane = t & 63;
    const int lm   = lane & 15;
    const int lq   = lane >> 4;

    const int nt  = blockIdx.x & 127;
    const int ks  = blockIdx.x >> 7;
    const int r0  = nt * 32;
    const int kb0 = ks * KPER;

    f32x4 acc[4];
    const f32x4 zero4 = {0.f, 0.f, 0.f, 0.f};
#pragma unroll
    for (int i = 0; i < 4; ++i) acc[i] = zero4;

    // staging maps: A: 64 rows x 4 segs of 16 bf16; W: 32 rows x 8 segs of 8 ints
    const int uAr = t >> 2, uAc = (t & 3) * 16;
    const int uWr = t >> 3, uWc = (t & 7) * 8;

    const unsigned short* pA = Abf + (size_t)uAr * IC + kb0 + uAc;
    const int*            pW = wp  + (size_t)(r0 + uWr) * IC + kb0 + uWc;

    // preload iter 0
    int4 a0 = *(const int4*)(pA);
    int4 a1 = *(const int4*)(pA + 8);
    int4 w0 = *(const int4*)(pW);
    int4 w1 = *(const int4*)(pW + 4);

    for (int it = 0; it < NITER; ++it) {
        __syncthreads();   // previous iteration's LDS reads complete

        *(int4*)(&lA[uAr * LDK + uAc])     = a0;
        *(int4*)(&lA[uAr * LDK + uAc + 8]) = a1;

        // bytes are 0..255, so (x>>4) is already the hi nibble (no mask)
        int4 lo, hi;
        lo.x = pack2bf(w0.x & 15, w0.y & 15);
        lo.y = pack2bf(w0.z & 15, w0.w & 15);
        lo.z = pack2bf(w1.x & 15, w1.y & 15);
        lo.w = pack2bf(w1.z & 15, w1.w & 15);
        hi.x = pack2bf(w0.x >> 4, w0.y >> 4);
        hi.y = pack2bf(w0.z >> 4, w0.w >> 4);
        hi.z = pack2bf(w1.x >> 4, w1.y >> 4);
        hi.w = pack2bf(w1.z >> 4, w1.w >> 4);
        *(int4*)(&lW[uWr        * LDK + uWc]) = lo;
        *(int4*)(&lW[(uWr + 32) * LDK + uWc]) = hi;

        __syncthreads();

        // preload next iter (wrapped on last iter; values unused)
        {
            const int koff = ((it + 1) & (NITER - 1)) * BK;
            a0 = *(const int4*)(pA + koff);
            a1 = *(const int4*)(pA + koff + 8);
            w0 = *(const int4*)(pW + koff);
            w1 = *(const int4*)(pW + koff + 4);
        }

#pragma unroll
        for (int s = 0; s < 2; ++s) {
            const int kc = s * 32 + lq * 8;
            const bf16x8 bfrg = *(const bf16x8*)(&lW[(wave * 16 + lm) * LDK + kc]);
#pragma unroll
            for (int mt = 0; mt < 4; ++mt) {
                const bf16x8 afrg = *(const bf16x8*)(&lA[(mt * 16 + lm) * LDK + kc]);
                acc[mt] = __builtin_amdgcn_mfma_f32_16x16x32_bf16(afrg, bfrg, acc[mt], 0, 0, 0);
            }
        }
    }

    // Epilogue: raw partial stores (wave-coalesced 256B per inst).
    // C/D layout: col(n) = lane&15, row(m within tile) = lq*4 + reg.
    const int cr = wave * 16 + lm;
    const int ch = (cr < 32) ? (r0 + cr) : (OCH + r0 + (cr - 32));
    float* pout = part + (size_t)ks * (BATCH * OC) + ch;

#pragma unroll
    for (int mt = 0; mt < 4; ++mt) {
#pragma unroll
        for (int r = 0; r < 4; ++r) {
            const int m = mt * 16 + lq * 4 + r;
            pout[(size_t)m * OC] = acc[mt][r];
        }
    }
}

// ---------------------------------------------------------------------------
// Reduce: out[m][ch] = delta[ch]*dot + bias[ch] - delta[ch]*zp[ch]*S[m]
// Sums KSPLIT partials; fully overwrites d_out (no memset needed).
// ---------------------------------------------------------------------------
__global__ __launch_bounds__(256) void reduce_kernel(
    const float* __restrict__ part,   // [KSPLIT][64][8192]
    const float* __restrict__ delta,
    const float* __restrict__ zp,
    const float* __restrict__ bias,
    const float* __restrict__ S,      // [64]
    float* __restrict__ out)          // [64][8192]
{
    const int e  = (blockIdx.x * 256 + threadIdx.x) * 4;
    const int m  = e >> 13;           // / 8192
    const int ch = e & (OC - 1);

    float4 s = {0.f, 0.f, 0.f, 0.f};
#pragma unroll
    for (int k = 0; k < KSPLIT; ++k) {
        const float4 p = *(const float4*)(part + (size_t)k * (BATCH * OC) + e);
        s.x += p.x; s.y += p.y; s.z += p.z; s.w += p.w;
    }
    const float4 d = *(const float4*)(delta + ch);
    const float4 z = *(const float4*)(zp + ch);
    const float4 b = *(const float4*)(bias + ch);
    const float Sm = S[m];

    float4 o;
    o.x = d.x * s.x + b.x - d.x * z.x * Sm;
    o.y = d.y * s.y + b.y - d.y * z.y * Sm;
    o.z = d.z * s.z + b.z - d.z * z.z * Sm;
    o.w = d.w * s.w + b.w - d.w * z.w * Sm;
    *(float4*)(out + e) = o;
}

extern "C" void kernel_launch(void* const* d_in, const int* in_sizes, int n_in,
                              void* d_out, int out_size, void* d_ws, size_t ws_size,
                              hipStream_t stream) {
    const float* input = (const float*)d_in[0];
    const int*   wpk   = (const int*)d_in[1];
    const float* delta = (const float*)d_in[2];
    const float* zp    = (const float*)d_in[3];
    const float* bias  = (const float*)d_in[4];
    float* out = (float*)d_out;

    // ws layout: Abf (1 MiB) | S (4 KiB slot) | partial (16 MiB)
    unsigned short* Abf = (unsigned short*)d_ws;
    float* S    = (float*)((char*)d_ws + (size_t)BATCH * IC * 2);
    float* part = (float*)((char*)d_ws + (size_t)BATCH * IC * 2 + 4096);

    prep_kernel<<<dim3(BATCH), dim3(256), 0, stream>>>(input, Abf, S);
    gemm_kernel<<<dim3(128 * KSPLIT), dim3(256), 0, stream>>>(Abf, wpk, part);
    reduce_kernel<<<dim3(BATCH * OC / 1024), dim3(256), 0, stream>>>(part, delta, zp, bias, S, out);
}

// Round 4
// 218.722 us; speedup vs baseline: 1.0382x; 1.0303x over previous
//
#include <hip/hip_runtime.h>

// Problem constants
constexpr int BATCH = 64;     // M
constexpr int IC    = 8192;   // K
constexpr int OC    = 8192;   // N
constexpr int OCH   = 4096;   // packed rows (OC/2)
constexpr int KSPLIT = 4;
constexpr int KPER  = IC / KSPLIT;   // 2048
constexpr int BK    = 64;            // K-chunk staged in LDS
constexpr int NITER = KPER / BK;     // 32
constexpr int LDK   = BK + 8;        // 72: fragment reads spread uniformly (8 dw/bank, b128 floor)

typedef __bf16 bf16x8 __attribute__((ext_vector_type(8)));
typedef float  f32x4  __attribute__((ext_vector_type(4)));

// fp32 -> bf16 round-to-nearest-even
static __device__ __forceinline__ unsigned short f2bf(float f) {
    unsigned u = __float_as_uint(f);
    u += 0x7FFFu + ((u >> 16) & 1u);
    return (unsigned short)(u >> 16);
}

// (bf16(n1)<<16) | bf16(n0) for small ints 0..15 (fp32 truncation exact)
static __device__ __forceinline__ unsigned pack2bf(int n0, int n1) {
    unsigned f0 = __float_as_uint((float)n0);
    unsigned f1 = __float_as_uint((float)n1);
    return __builtin_amdgcn_perm(f1, f0, 0x07060302u);
}

// ---------------------------------------------------------------------------
// Prep: input fp32 [64,8192] -> bf16 in ws, plus per-row sums S[64]
// ---------------------------------------------------------------------------
__global__ __launch_bounds__(256) void prep_kernel(
    const float* __restrict__ in, unsigned short* __restrict__ Abf,
    float* __restrict__ S)
{
    const int b = blockIdx.x;
    const int t = threadIdx.x;
    const float* row = in + (size_t)b * IC;
    unsigned short* orow = Abf + (size_t)b * IC;

    float sum = 0.f;
#pragma unroll
    for (int i = 0; i < IC / 1024; ++i) {
        const int c = i * 1024 + t * 4;
        const float4 v = *(const float4*)(row + c);
        sum += (v.x + v.y) + (v.z + v.w);
        ushort4 o = make_ushort4(f2bf(v.x), f2bf(v.y), f2bf(v.z), f2bf(v.w));
        *(ushort4*)(orow + c) = o;
    }
#pragma unroll
    for (int off = 32; off > 0; off >>= 1) sum += __shfl_down(sum, off);

    __shared__ float red[4];
    if ((t & 63) == 0) red[t >> 6] = sum;
    __syncthreads();
    if (t == 0) S[b] = (red[0] + red[1]) + (red[2] + red[3]);
}

// ---------------------------------------------------------------------------
// GEMM: partial[ks][64][8192] = A.Q^T over this split's K-range.
// 512 blocks (128 n-tiles x 4 k-splits). Tile M=64 x N=64 (lo+hi nibbles of
// 32 packed rows; each packed int32 fetched exactly once device-wide).
// Single-barrier double-buffered LDS K-loop: while computing from buf[p],
// the next chunk's global loads drain and are unpacked/written into buf[1-p];
// the barrier only orders LDS writes, never the global-load wait.
// ---------------------------------------------------------------------------
__global__ __launch_bounds__(256, 2) void gemm_kernel(
    const unsigned short* __restrict__ Abf,   // bf16 [64][8192]
    const int* __restrict__ wp,               // packed [4096][8192]
    float* __restrict__ part)                 // fp32 [KSPLIT][64][8192]
{
    __shared__ unsigned short lA[2][64 * LDK];
    __shared__ unsigned short lW[2][64 * LDK];  // rows 0..31 lo nibble, 32..63 hi

    const int t    = threadIdx.x;
    const int wave = t >> 6;
    const int lane = t & 63;
    const int lm   = lane & 15;
    const int lq   = lane >> 4;

    const int nt  = blockIdx.x & 127;
    const int ks  = blockIdx.x >> 7;
    const int r0  = nt * 32;
    const int kb0 = ks * KPER;

    f32x4 acc[4];
    const f32x4 zero4 = {0.f, 0.f, 0.f, 0.f};
#pragma unroll
    for (int i = 0; i < 4; ++i) acc[i] = zero4;

    // staging maps: A: 64 rows x 4 segs of 16 bf16; W: 32 rows x 8 segs of 8 ints
    const int uAr = t >> 2, uAc = (t & 3) * 16;
    const int uWr = t >> 3, uWc = (t & 7) * 8;

    const unsigned short* pA = Abf + (size_t)uAr * IC + kb0 + uAc;
    const int*            pW = wp  + (size_t)(r0 + uWr) * IC + kb0 + uWc;

    // ---- prologue: load + stage iter 0 into buf 0 ----
    int4 a0 = *(const int4*)(pA);
    int4 a1 = *(const int4*)(pA + 8);
    int4 w0 = *(const int4*)(pW);
    int4 w1 = *(const int4*)(pW + 4);

    {
        *(int4*)(&lA[0][uAr * LDK + uAc])     = a0;
        *(int4*)(&lA[0][uAr * LDK + uAc + 8]) = a1;
        int4 lo, hi;
        lo.x = pack2bf(w0.x & 15, w0.y & 15);
        lo.y = pack2bf(w0.z & 15, w0.w & 15);
        lo.z = pack2bf(w1.x & 15, w1.y & 15);
        lo.w = pack2bf(w1.z & 15, w1.w & 15);
        hi.x = pack2bf(w0.x >> 4, w0.y >> 4);
        hi.y = pack2bf(w0.z >> 4, w0.w >> 4);
        hi.z = pack2bf(w1.x >> 4, w1.y >> 4);
        hi.w = pack2bf(w1.z >> 4, w1.w >> 4);
        *(int4*)(&lW[0][uWr        * LDK + uWc]) = lo;
        *(int4*)(&lW[0][(uWr + 32) * LDK + uWc]) = hi;
    }
    __syncthreads();

    for (int it = 0; it < NITER; ++it) {
        const int p = it & 1;

        // issue global loads for iter it+1 (wrap on last; values unused)
        const int koff = ((it + 1) & (NITER - 1)) * BK;
        a0 = *(const int4*)(pA + koff);
        a1 = *(const int4*)(pA + koff + 8);
        w0 = *(const int4*)(pW + koff);
        w1 = *(const int4*)(pW + koff + 4);

        // compute from buf[p] while the loads fly
#pragma unroll
        for (int s = 0; s < 2; ++s) {
            const int kc = s * 32 + lq * 8;
            const bf16x8 bfrg = *(const bf16x8*)(&lW[p][(wave * 16 + lm) * LDK + kc]);
#pragma unroll
            for (int mt = 0; mt < 4; ++mt) {
                const bf16x8 afrg = *(const bf16x8*)(&lA[p][(mt * 16 + lm) * LDK + kc]);
                acc[mt] = __builtin_amdgcn_mfma_f32_16x16x32_bf16(afrg, bfrg, acc[mt], 0, 0, 0);
            }
        }

        // stage iter it+1 into buf[1-p] (safe: all reads of buf[1-p] finished
        // before the barrier at the end of iter it-1)
        *(int4*)(&lA[1 - p][uAr * LDK + uAc])     = a0;
        *(int4*)(&lA[1 - p][uAr * LDK + uAc + 8]) = a1;
        int4 lo, hi;
        lo.x = pack2bf(w0.x & 15, w0.y & 15);
        lo.y = pack2bf(w0.z & 15, w0.w & 15);
        lo.z = pack2bf(w1.x & 15, w1.y & 15);
        lo.w = pack2bf(w1.z & 15, w1.w & 15);
        hi.x = pack2bf(w0.x >> 4, w0.y >> 4);
        hi.y = pack2bf(w0.z >> 4, w0.w >> 4);
        hi.z = pack2bf(w1.x >> 4, w1.y >> 4);
        hi.w = pack2bf(w1.z >> 4, w1.w >> 4);
        *(int4*)(&lW[1 - p][uWr        * LDK + uWc]) = lo;
        *(int4*)(&lW[1 - p][(uWr + 32) * LDK + uWc]) = hi;

        __syncthreads();
    }

    // Epilogue: raw partial stores (wave-coalesced).
    // C/D layout: col(n) = lane&15, row(m within tile) = lq*4 + reg.
    const int cr = wave * 16 + lm;
    const int ch = (cr < 32) ? (r0 + cr) : (OCH + r0 + (cr - 32));
    float* pout = part + (size_t)ks * (BATCH * OC) + ch;

#pragma unroll
    for (int mt = 0; mt < 4; ++mt) {
#pragma unroll
        for (int r = 0; r < 4; ++r) {
            const int m = mt * 16 + lq * 4 + r;
            pout[(size_t)m * OC] = acc[mt][r];
        }
    }
}

// ---------------------------------------------------------------------------
// Reduce: out[m][ch] = delta[ch]*dot + bias[ch] - delta[ch]*zp[ch]*S[m]
// Sums KSPLIT partials; fully overwrites d_out (no memset needed).
// ---------------------------------------------------------------------------
__global__ __launch_bounds__(256) void reduce_kernel(
    const float* __restrict__ part,   // [KSPLIT][64][8192]
    const float* __restrict__ delta,
    const float* __restrict__ zp,
    const float* __restrict__ bias,
    const float* __restrict__ S,      // [64]
    float* __restrict__ out)          // [64][8192]
{
    const int e  = (blockIdx.x * 256 + threadIdx.x) * 4;
    const int m  = e >> 13;           // / 8192
    const int ch = e & (OC - 1);

    float4 s = {0.f, 0.f, 0.f, 0.f};
#pragma unroll
    for (int k = 0; k < KSPLIT; ++k) {
        const float4 p = *(const float4*)(part + (size_t)k * (BATCH * OC) + e);
        s.x += p.x; s.y += p.y; s.z += p.z; s.w += p.w;
    }
    const float4 d = *(const float4*)(delta + ch);
    const float4 z = *(const float4*)(zp + ch);
    const float4 b = *(const float4*)(bias + ch);
    const float Sm = S[m];

    float4 o;
    o.x = d.x * s.x + b.x - d.x * z.x * Sm;
    o.y = d.y * s.y + b.y - d.y * z.y * Sm;
    o.z = d.z * s.z + b.z - d.z * z.z * Sm;
    o.w = d.w * s.w + b.w - d.w * z.w * Sm;
    *(float4*)(out + e) = o;
}

extern "C" void kernel_launch(void* const* d_in, const int* in_sizes, int n_in,
                              void* d_out, int out_size, void* d_ws, size_t ws_size,
                              hipStream_t stream) {
    const float* input = (const float*)d_in[0];
    const int*   wpk   = (const int*)d_in[1];
    const float* delta = (const float*)d_in[2];
    const float* zp    = (const float*)d_in[3];
    const float* bias  = (const float*)d_in[4];
    float* out = (float*)d_out;

    // ws layout: Abf (1 MiB) | S (4 KiB slot) | partial (8 MiB)
    unsigned short* Abf = (unsigned short*)d_ws;
    float* S    = (float*)((char*)d_ws + (size_t)BATCH * IC * 2);
    float* part = (float*)((char*)d_ws + (size_t)BATCH * IC * 2 + 4096);

    prep_kernel<<<dim3(BATCH), dim3(256), 0, stream>>>(input, Abf, S);
    gemm_kernel<<<dim3(128 * KSPLIT), dim3(256), 0, stream>>>(Abf, wpk, part);
    reduce_kernel<<<dim3(BATCH * OC / 1024), dim3(256), 0, stream>>>(part, delta, zp, bias, S, out);
}